// Round 16
// baseline (1956.617 us; speedup 1.0000x reference)
//
#include <hip/hip_runtime.h>
#include <hip/hip_bf16.h>
#include <math.h>

#define TPB 256

typedef __attribute__((ext_vector_type(8))) short s16x8;
typedef __attribute__((ext_vector_type(8))) unsigned short u16x8;
typedef __attribute__((ext_vector_type(4))) float f32x4;

// =====================================================================================
// RUN-0 conv3x3 — EXACT R11 kernel (889us, VGPR 20, occ 67%; best of the R11-R14 sweep:
// occupancy dominates ILP on this latency-bound gather). FP statements R4-frozen;
// wave-remap + XCD remap validated. PERMANENTLY CLOSED.
// =====================================================================================
__global__ void conv3x3s2_r0_k(const float* __restrict__ in, const float* __restrict__ w,
                               const float* __restrict__ bias, float* __restrict__ out)
{
  const int d = blockIdx.x;
  const int xcd = d & 7;
  const int n = xcd & 3;
  const int ipair = ((d >> 3) << 1) | (xcd >> 2);
  const int wave = ipair * 4 + (threadIdx.x >> 6);   // [0, 1596) = 57 oc-tiles x 28 oy
  const int oct = wave % 57;
  const int oy = wave / 57;
  const int lane = threadIdx.x & 63;
  const int oc_low = lane / 7;                        // 0..8 active, 9 (lane 63) idle
  const int oxg = lane - oc_low * 7;
  const int oc = oct * 9 + oc_low;
  if (oc_low > 8 || oc >= 512) return;

  const float* inp = in + (size_t)n * 256 * 3136;
  const float* wp = w + (size_t)oc * 2304;
  float b0 = bias[oc];
  float acc0 = b0, acc1 = b0, acc2 = b0, acc3 = b0;
  int xb0 = oxg * 8;
  #pragma unroll 4
  for (int ic = 0; ic < 256; ic++) {
    const float* ich = inp + (size_t)ic * 3136;
    const float* wr = wp + ic * 9;
    #pragma unroll
    for (int ky = 0; ky < 3; ky++) {
      int iy = oy * 2 + ky;
      if (iy >= 56) continue;
      const float* row = ich + iy * 56;
      float w0 = wr[ky * 3 + 0], w1 = wr[ky * 3 + 1], w2 = wr[ky * 3 + 2];
      {
        int xb = xb0 + 0;
        acc0 += row[xb] * w0 + row[xb + 1] * w1 + row[xb + 2] * w2;
      }
      {
        int xb = xb0 + 2;
        acc1 += row[xb] * w0 + row[xb + 1] * w1 + row[xb + 2] * w2;
      }
      {
        int xb = xb0 + 4;
        acc2 += row[xb] * w0 + row[xb + 1] * w1 + row[xb + 2] * w2;
      }
      {
        int xb = xb0 + 6;
        acc3 += row[xb] * w0 + row[xb + 1] * w1;
        if (xb + 2 < 56) acc3 += row[xb + 2] * w2;
      }
    }
  }
  float* op = out + (((size_t)n * 512 + oc) * 28 + oy) * 28 + oxg * 4;
  op[0] = fmaxf(acc0, 0.f);
  op[1] = fmaxf(acc1, 0.f);
  op[2] = fmaxf(acc2, 0.f);
  op[3] = fmaxf(acc3, 0.f);
}

// =====================================================================================
// fp32 implicit-GEMM conv (BM=128), BINIT bias-seeded: bit-exact single-fma chain
// (R6-validated). Used for run-0 conv7x7 only.
// =====================================================================================
template<int KH, int KW, int STRIDE, int PADL, bool BINIT>
__global__ __launch_bounds__(256)
void conv_igemm_k(const float* __restrict__ in, const float* __restrict__ w,
                  const float* __restrict__ bias, float* __restrict__ out,
                  int Cin, int Cout, int Hin, int OH, int Np, int K)
{
  __shared__ float As[16][136];
  __shared__ float Bs[16][64];

  const int tid = threadIdx.x;
  const int bx = blockIdx.x;
  const int by = blockIdx.y;
  const int OHW = OH * OH;
  const int HinHin = Hin * Hin;

  const int n_sub = tid & 63;
  const int kq = tid >> 6;
  const int n_g = bx * 64 + n_sub;
  const bool nvalid = (n_g < Np);
  const int n_c = nvalid ? n_g : 0;
  const int img = n_c / OHW;
  const int p = n_c - img * OHW;
  const int oy = p / OH;
  const int ox = p - oy * OH;
  const int iy0 = oy * STRIDE - PADL;
  const int ix0 = ox * STRIDE - PADL;
  const float* inb = in + (size_t)img * Cin * HinHin;

  const int ks = tid & 15;
  const int msq = tid >> 4;
  const int m_base = by * 128;

  const int m0 = (tid >> 4) * 8;
  const int n0 = (tid & 15) * 4;

  float acc[8][4];
  #pragma unroll
  for (int i = 0; i < 8; i++) {
    const float init = BINIT ? bias[m_base + m0 + i] : 0.f;
    #pragma unroll
    for (int j = 0; j < 4; j++) acc[i][j] = init;
  }

  const int KT = (K + 15) >> 4;
  for (int kt = 0; kt < KT; kt++) {
    const int k0 = kt * 16;
    #pragma unroll
    for (int j = 0; j < 8; j++) {
      const int m = msq + 16 * j;
      const int k = k0 + ks;
      float v = 0.f;
      if (k < K) v = w[(size_t)(m_base + m) * K + k];
      As[ks][m] = v;
    }
    #pragma unroll
    for (int j = 0; j < 4; j++) {
      const int k = k0 + kq * 4 + j;
      float v = 0.f;
      if (nvalid && k < K) {
        const int c = k / (KH * KW);
        const int r = k - c * (KH * KW);
        const int ky = r / KW;
        const int kx = r - ky * KW;
        const int iy = iy0 + ky;
        const int ix = ix0 + kx;
        if (iy >= 0 && iy < Hin && ix >= 0 && ix < Hin)
          v = inb[(size_t)c * HinHin + iy * Hin + ix];
      }
      Bs[kq * 4 + j][n_sub] = v;
    }
    __syncthreads();
    #pragma unroll
    for (int k = 0; k < 16; k++) {
      float a_[8], b_[4];
      #pragma unroll
      for (int i = 0; i < 8; i++) a_[i] = As[k][m0 + i];
      #pragma unroll
      for (int j = 0; j < 4; j++) b_[j] = Bs[k][n0 + j];
      #pragma unroll
      for (int i = 0; i < 8; i++)
        #pragma unroll
        for (int j = 0; j < 4; j++) acc[i][j] += a_[i] * b_[j];
    }
    __syncthreads();
  }

  #pragma unroll
  for (int i = 0; i < 8; i++) {
    const int m = m_base + m0 + i;
    const float bv = BINIT ? 0.f : bias[m];
    #pragma unroll
    for (int j = 0; j < 4; j++) {
      const int nn = bx * 64 + n0 + j;
      if (nn < Np) {
        const int img2 = nn / OHW;
        const int pp = nn - img2 * OHW;
        const float v = BINIT ? acc[i][j] : (acc[i][j] + bv);
        out[((size_t)img2 * Cout + m) * OHW + pp] = fmaxf(v, 0.f);
      }
    }
  }
}

// =====================================================================================
// 1x1 stride-2 conv as GEMM, BM=32/BN=64/BK=32, bias-seeded bit-exact fma chain
// (R10-validated). Run-0 conv3/conv4.
// =====================================================================================
__global__ __launch_bounds__(256)
void conv1x1_igemm32_k(const float* __restrict__ in, const float* __restrict__ w,
                       const float* __restrict__ bias, float* __restrict__ out,
                       int Cin, int Cout, int Hin, int OH, int Np)
{
  __shared__ float As[32][33];   // [k][m]
  __shared__ float Bs[32][65];   // [k][n]

  const int tid = threadIdx.x;
  const int bx = blockIdx.x;
  const int by = blockIdx.y;
  const int OHW = OH * OH;
  const int HH = Hin * Hin;
  const int m_base = by * 32;

  const int am = tid >> 3;
  const int ak0 = (tid & 7) * 4;
  const int bk = tid >> 3;
  const int bn0 = (tid & 7) * 8;
  const int cn = tid & 63;
  const int cm0 = (tid >> 6) * 8;
  const int n_g = bx * 64 + cn;

  float acc[8];
  #pragma unroll
  for (int i = 0; i < 8; i++) acc[i] = bias[m_base + cm0 + i];

  int bpix[8]; bool bval[8];
  #pragma unroll
  for (int j = 0; j < 8; j++) {
    int n = bx * 64 + bn0 + j;
    bval[j] = (n < Np);
    int nn = bval[j] ? n : 0;
    int img = nn / OHW; int pp = nn - img * OHW; int oy = pp / OH; int ox = pp - oy * OH;
    bpix[j] = img * Cin * HH + (2 * oy) * Hin + 2 * ox;
  }

  for (int k0 = 0; k0 < Cin; k0 += 32) {
    #pragma unroll
    for (int j = 0; j < 4; j++)
      As[ak0 + j][am] = w[(size_t)(m_base + am) * Cin + k0 + ak0 + j];
    #pragma unroll
    for (int j = 0; j < 8; j++)
      Bs[bk][bn0 + j] = bval[j] ? in[(size_t)(k0 + bk) * HH + bpix[j]] : 0.f;
    __syncthreads();
    #pragma unroll
    for (int k = 0; k < 32; k++) {
      float b = Bs[k][cn];
      #pragma unroll
      for (int i = 0; i < 8; i++) acc[i] += As[k][cm0 + i] * b;
    }
    __syncthreads();
  }

  if (n_g < Np) {
    int img = n_g / OHW; int pp = n_g - img * OHW;
    #pragma unroll
    for (int i = 0; i < 8; i++)
      out[((size_t)img * Cout + m_base + cm0 + i) * OHW + pp] = fmaxf(acc[i], 0.f);
  }
}

// =====================================================================================
// fp32 -> bf16 weight conversion (RNE); padded variant zero-fills k in [kin, kout)
// =====================================================================================
__global__ void cvt_bf16_k(const float* __restrict__ in, unsigned short* __restrict__ out, int n)
{
  int i = blockIdx.x * blockDim.x + threadIdx.x;
  if (i >= n) return;
  __hip_bfloat16 h = __float2bfloat16(in[i]);
  out[i] = *reinterpret_cast<unsigned short*>(&h);
}

__global__ void cvt_bf16_pad_k(const float* __restrict__ in, unsigned short* __restrict__ out,
                               int rows, int kin, int kout)
{
  int i = blockIdx.x * blockDim.x + threadIdx.x;
  if (i >= rows * kout) return;
  int r = i / kout, k = i - r * kout;
  unsigned short v = 0;
  if (k < kin) {
    __hip_bfloat16 h = __float2bfloat16(in[(size_t)r * kin + k]);
    v = *reinterpret_cast<unsigned short*>(&h);
  }
  out[i] = v;
}

// =====================================================================================
// fmap transpose: (4,2048,49) -> (4,49,2048). Pure data movement (bit-exact).
// =====================================================================================
__global__ void transpose_fm_k(const float* __restrict__ in, float* __restrict__ out)
{
  int idx = blockIdx.x * blockDim.x + threadIdx.x;
  if (idx >= 4 * 49 * 2048) return;
  const int c = idx & 2047;
  const int t = idx >> 11;          // b*49 + p
  const int b = t / 49;
  const int p = t - b * 49;
  out[idx] = in[((size_t)b * 2048 + c) * 49 + p];
}

// =====================================================================================
// bf16 MFMA implicit-GEMM conv, BM=256 x BN=64, BK=32, software-pipelined gather.
// 4 m-subtiles per block -> B-gather issued half as often as BM=128 (R11 mfma2);
// per-output k-accumulation sequence identical -> bit-identical outputs.
// Cout must be a multiple of 256 (256/512/1024/2048 all are).
// =====================================================================================
template<int KH, int KW, int STRIDE, int PADL>
__global__ __launch_bounds__(256)
void conv_mfma4_k(const float* __restrict__ in, const unsigned short* __restrict__ wbf,
                  const float* __restrict__ bias, float* __restrict__ out,
                  int Cin, int Cout, int Hin, int OH, int Np, int K, int kreal)
{
  __shared__ unsigned short As[256 * 40];  // [m][k], rows padded to 40
  __shared__ unsigned short Bs[64 * 40];   // [n][k]

  const int tid = threadIdx.x;
  const int bx = blockIdx.x;
  const int by = blockIdx.y;
  const int OHW = OH * OH;
  const int HH = Hin * Hin;
  const int m_base = by * 256;

  const int n_sub = tid & 63;
  const int kq = tid >> 6;
  const int n_g = bx * 64 + n_sub;
  const bool nv = (n_g < Np);
  const int n_c = nv ? n_g : 0;
  const int img = n_c / OHW;
  const int p = n_c - img * OHW;
  const int oy = p / OH;
  const int ox = p - oy * OH;
  const int iy0 = oy * STRIDE - PADL;
  const int ix0 = ox * STRIDE - PADL;
  const float* inb = in + (size_t)img * Cin * HH;

  const int wv = tid >> 6;
  const int ln = tid & 63;
  const int lr = ln & 15;
  const int lq = ln >> 4;

  f32x4 acc[4][4];
  #pragma unroll
  for (int h = 0; h < 4; h++)
    #pragma unroll
    for (int nf = 0; nf < 4; nf++) acc[h][nf] = (f32x4){0.f, 0.f, 0.f, 0.f};

  // A: thread stages its own full 32-k row (arow = tid), 4 x u16x8
#define GATHER_A(K0, AV)                                                          \
  {                                                                               \
    const unsigned short* wr_ = wbf + (size_t)(m_base + tid) * K + (K0);          \
    AV[0] = *(const u16x8*)(wr_);                                                 \
    AV[1] = *(const u16x8*)(wr_ + 8);                                             \
    AV[2] = *(const u16x8*)(wr_ + 16);                                            \
    AV[3] = *(const u16x8*)(wr_ + 24);                                            \
  }
#define GATHER_B(K0, BV)                                                          \
  {                                                                               \
    _Pragma("unroll")                                                             \
    for (int i = 0; i < 8; i++) {                                                 \
      const int k = (K0) + kq * 8 + i;                                            \
      float v = 0.f;                                                              \
      if (nv && k < kreal) {                                                      \
        const int c = k / (KH * KW);                                              \
        const int r = k - c * (KH * KW);                                          \
        const int ky = r / KW;                                                    \
        const int kx = r - ky * KW;                                               \
        const int iy = iy0 + ky;                                                  \
        const int ix = ix0 + kx;                                                  \
        if (iy >= 0 && iy < Hin && ix >= 0 && ix < Hin)                           \
          v = inb[(size_t)c * HH + iy * Hin + ix];                                \
      }                                                                           \
      __hip_bfloat16 h_ = __float2bfloat16(v);                                    \
      BV[i] = *reinterpret_cast<unsigned short*>(&h_);                            \
    }                                                                             \
  }

  u16x8 av[4], bv;
  GATHER_A(0, av);
  GATHER_B(0, bv);

  for (int k0 = 0; k0 < K; k0 += 32) {
    #pragma unroll
    for (int j = 0; j < 4; j++) *(u16x8*)&As[tid * 40 + j * 8] = av[j];
    *(u16x8*)&Bs[n_sub * 40 + kq * 8] = bv;
    __syncthreads();

    if (k0 + 32 < K) { GATHER_A(k0 + 32, av); GATHER_B(k0 + 32, bv); }

    s16x8 am[4];
    #pragma unroll
    for (int h = 0; h < 4; h++)
      am[h] = *(const s16x8*)&As[(h * 64 + wv * 16 + lr) * 40 + lq * 8];
    #pragma unroll
    for (int nf = 0; nf < 4; nf++) {
      s16x8 b = *(const s16x8*)&Bs[(nf * 16 + lr) * 40 + lq * 8];
      #pragma unroll
      for (int h = 0; h < 4; h++)
        acc[h][nf] = __builtin_amdgcn_mfma_f32_16x16x32_bf16(am[h], b, acc[h][nf], 0, 0, 0);
    }
    __syncthreads();
  }
#undef GATHER_A
#undef GATHER_B

  #pragma unroll
  for (int h = 0; h < 4; h++) {
    #pragma unroll
    for (int nf = 0; nf < 4; nf++) {
      const int n_gl = bx * 64 + nf * 16 + lr;
      if (n_gl < Np) {
        const int img2 = n_gl / OHW;
        const int pp = n_gl - img2 * OHW;
        #pragma unroll
        for (int r = 0; r < 4; r++) {
          const int m = m_base + h * 64 + wv * 16 + lq * 4 + r;
          out[((size_t)img2 * Cout + m) * OHW + pp] = fmaxf(acc[h][nf][r] + bias[m], 0.f);
        }
      }
    }
  }
}

// ---------------- global average pool (X,2048,7,7) -> (X,2048)
__global__ void pool_k(const float* __restrict__ in, float* __restrict__ out, int total)
{
  int idx = blockIdx.x * blockDim.x + threadIdx.x;
  if (idx >= total) return;
  const float* p = in + (size_t)idx * 49;
  float s = 0.f;
  #pragma unroll
  for (int i = 0; i < 49; i++) s += p[i];
  out[idx] = s / 49.f;
}

// ---------------- gf = gvec @ wc.T + bc (DECISION PATH: serial c-order chain, frozen)
__global__ void gf_k(const float* __restrict__ gvec,
                     const float* __restrict__ w_ord, const float* __restrict__ b_ord,
                     const float* __restrict__ w_fam, const float* __restrict__ b_fam,
                     const float* __restrict__ w_sp,  const float* __restrict__ b_sp,
                     float* __restrict__ gfbuf)
{
  int idx = blockIdx.x * blockDim.x + threadIdx.x;
  if (idx >= 12 * 256) return;
  int o = idx % 256; int t = idx / 256; int b = t % 4; int s = t / 4;
  int nc = (s == 0) ? 13 : ((s == 1) ? 38 : 200);
  if (o >= nc) return;
  const float* w = (s == 0) ? w_ord : ((s == 1) ? w_fam : w_sp);
  const float* bb = (s == 0) ? b_ord : ((s == 1) ? b_fam : b_sp);
  float acc = bb[o];
  const float* g = gvec + (size_t)b * 2048;
  const float* wr = w + (size_t)o * 2048;
  for (int c = 0; c < 2048; c++) acc += g[c] * wr[c];
  gfbuf[idx] = acc;
}

// ---------------- obj_loc, faithful to the JAX reference (serial, one thread)
__device__ void obj_loc_dev(const float* sc, int* zmin_o, int* zmax_o)
{
  const int n = 224, minsize = 28, defmax = 196;
  float mn = sc[0], mx = sc[0];
  for (int i = 1; i < n; i++) { mn = fminf(mn, sc[i]); mx = fmaxf(mx, sc[i]); }
  float den = (mx == mn) ? mx : (mx - mn);
#define NV(i) (((mx == mn) ? sc[i] : (sc[i] - mn)) / den)
#define SGN(v) (((v) > 0.5f) ? 1 : (((v) < 0.5f) ? -1 : 0))

  int k = 0; float M = -INFINITY;
  {
    float v = NV(0); int sg = SGN(v);
    float smax = -INFINITY; int cnt = 0;
    for (int j = 0; j < n; j++) {
      int indj = 0; float vn = 0.f; int sgn_nx = 0;
      if (j < n - 1) { vn = NV(j + 1); sgn_nx = SGN(vn); int d = sgn_nx - sg; indj = (d == 2 || d == -2); }
      if (indj) { if (cnt > 0) M = fmaxf(M, smax); k++; smax = -INFINITY; cnt = 0; }
      smax = fmaxf(smax, v); cnt++;
      if (j < n - 1) { v = vn; sg = sgn_nx; }
    }
    if (cnt > 0) M = fmaxf(M, smax);
  }

  int zmin, zmax;
  if (k == 0) { zmin = minsize; zmax = defmax; }
  else {
    int bestlen = -1;
    {
      float v = NV(0); int sg = SGN(v);
      float smax = -INFINITY; int cnt = 0;
      for (int j = 0; j < n; j++) {
        int indj = 0; float vn = 0.f; int sgn_nx = 0;
        if (j < n - 1) { vn = NV(j + 1); sgn_nx = SGN(vn); int d = sgn_nx - sg; indj = (d == 2 || d == -2); }
        if (indj) { if (cnt > 0 && smax == M && cnt > bestlen) bestlen = cnt; smax = -INFINITY; cnt = 0; }
        smax = fmaxf(smax, v); cnt++;
        if (j < n - 1) { v = vn; sg = sgn_nx; }
      }
      if (cnt > 0 && smax == M && cnt > bestlen) bestlen = cnt;
    }
    int bestorder = 1 << 30; int bzmin = 0, bzmax = 0;
    {
      float v = NV(0); int sg = SGN(v);
      float smax = -INFINITY; int cnt = 0; int start = 0; int sid = 0;
      for (int j = 0; j < n; j++) {
        int indj = 0; float vn = 0.f; int sgn_nx = 0;
        if (j < n - 1) { vn = NV(j + 1); sgn_nx = SGN(vn); int d = sgn_nx - sg; indj = (d == 2 || d == -2); }
        if (indj) {
          if (cnt > 0 && smax == M && cnt == bestlen) {
            int order = (sid == 0) ? 0 : ((sid == k) ? 1 : (sid + 1));
            if (order < bestorder) { bestorder = order; bzmin = start; bzmax = j; }
          }
          sid++; start = j; smax = -INFINITY; cnt = 0;
        }
        smax = fmaxf(smax, v); cnt++;
        if (j < n - 1) { v = vn; sg = sgn_nx; }
      }
      if (cnt > 0 && smax == M && cnt == bestlen) {
        int order = (sid == 0) ? 0 : ((sid == k) ? 1 : (sid + 1));
        if (order < bestorder) { bestorder = order; bzmin = start; bzmax = n; }
      }
    }
    zmin = bzmin; zmax = bzmax;
    int pad = minsize - (zmax - zmin);
    int hp = (pad + 1) / 2;
    int need = ((zmax - zmin) <= minsize);
    if (need && (zmin > hp) && ((n - zmax) > pad)) { zmin = zmin - hp + 1; zmax = zmax + hp; }
    if (need && (zmin < hp)) { zmin = 0; zmax = minsize; }
    if (need && ((n - zmax) < hp)) { zmin = n - minsize + 1; zmax = n; }
  }
  *zmin_o = zmin; *zmax_o = zmax;
#undef NV
#undef SGN
}

// ---------------- per (stage,batch): argmax, 7x7 CAM, upsample-max, obj_loc -> crops
// fmT is the transposed fmap (4,49,2048): phase-1 reads both operands contiguously in
// the SAME c order as before (bit-exact). R15-validated.
__global__ void cam_k(const float* __restrict__ fmT,      // (4,49,2048)
                      const float* __restrict__ gfbuf,    // (12,256)
                      const float* __restrict__ w_ord, const float* __restrict__ b_ord,
                      const float* __restrict__ w_fam, const float* __restrict__ b_fam,
                      const float* __restrict__ w_sp,  const float* __restrict__ b_sp,
                      int* __restrict__ crops)
{
  int bid = blockIdx.x;        // 0..11
  int s = bid / 4, b = bid % 4;
  int nc = (s == 0) ? 13 : ((s == 1) ? 38 : 200);
  const float* wc = (s == 0) ? w_ord : ((s == 1) ? w_fam : w_sp);
  const float* bc = (s == 0) ? b_ord : ((s == 1) ? b_fam : b_sp);

  __shared__ float cam7[49];
  __shared__ float wsc[224];
  __shared__ float hsc[224];
  __shared__ int top_s;
  int tid = threadIdx.x;

  if (tid == 0) {
    const float* g = gfbuf + (size_t)bid * 256;
    int best = 0; float bv = g[0];
    for (int i = 1; i < nc; i++) { if (g[i] > bv) { bv = g[i]; best = i; } }
    top_s = best;
  }
  __syncthreads();
  int top = top_s;

  if (tid < 49) {
    const float* fp = fmT + ((size_t)(b * 49) + tid) * 2048;
    const float* wr = wc + (size_t)top * 2048;
    float acc = bc[top];
    for (int c = 0; c < 2048; c++) acc += fp[c] * wr[c];
    cam7[tid] = 1.f / (1.f + expf(-acc));
  }
  __syncthreads();

  if (tid < 224) {
    {
      int xx = tid;
      float xsf = (float)(xx * 6) / 223.f;
      int xlo = (int)floorf(xsf); if (xlo > 6) xlo = 6; if (xlo < 0) xlo = 0;
      int xhi = xlo + 1; if (xhi > 6) xhi = 6;
      float xf = xsf - (float)xlo;
      float m = -INFINITY;
      for (int yy = 0; yy < 224; yy++) {
        float ysf = (float)(yy * 6) / 223.f;
        int ylo = (int)floorf(ysf); if (ylo > 6) ylo = 6; if (ylo < 0) ylo = 0;
        int yhi = ylo + 1; if (yhi > 6) yhi = 6;
        float yf = ysf - (float)ylo;
        float r0 = cam7[ylo * 7 + xlo] * (1.f - yf) + cam7[yhi * 7 + xlo] * yf;
        float r1 = cam7[ylo * 7 + xhi] * (1.f - yf) + cam7[yhi * 7 + xhi] * yf;
        m = fmaxf(m, r0 * (1.f - xf) + r1 * xf);
      }
      wsc[xx] = m;
    }
    {
      int yy = tid;
      float ysf = (float)(yy * 6) / 223.f;
      int ylo = (int)floorf(ysf); if (ylo > 6) ylo = 6; if (ylo < 0) ylo = 0;
      int yhi = ylo + 1; if (yhi > 6) yhi = 6;
      float yf = ysf - (float)ylo;
      float m = -INFINITY;
      for (int xx = 0; xx < 224; xx++) {
        float xsf = (float)(xx * 6) / 223.f;
        int xlo = (int)floorf(xsf); if (xlo > 6) xlo = 6; if (xlo < 0) xlo = 0;
        int xhi = xlo + 1; if (xhi > 6) xhi = 6;
        float xf = xsf - (float)xlo;
        float r0 = cam7[ylo * 7 + xlo] * (1.f - yf) + cam7[yhi * 7 + xlo] * yf;
        float r1 = cam7[ylo * 7 + xhi] * (1.f - yf) + cam7[yhi * 7 + xhi] * yf;
        m = fmaxf(m, r0 * (1.f - xf) + r1 * xf);
      }
      hsc[yy] = m;
    }
  }
  __syncthreads();

  if (tid == 0) {
    int zmin, zmax; obj_loc_dev(wsc, &zmin, &zmax);
    crops[bid * 4 + 0] = zmin; crops[bid * 4 + 1] = zmax;
  } else if (tid == 1) {
    int zmin, zmax; obj_loc_dev(hsc, &zmin, &zmax);
    crops[bid * 4 + 2] = zmin; crops[bid * 4 + 3] = zmax;
  }
}

// ---------------- bilinear (align_corners) crop-resize: inputs (4,3,224,224) -> lin (12,3,224,224)
__global__ void crop_resize_k(const float* __restrict__ in, const int* __restrict__ crops,
                              float* __restrict__ lin)
{
  int idx = blockIdx.x * blockDim.x + threadIdx.x;
  int total = 12 * 3 * 224 * 224;
  if (idx >= total) return;
  int xx = idx % 224; int t = idx / 224; int yy = t % 224; t /= 224; int c = t % 3; int img = t / 3;
  int b = img % 4;
  int x1 = crops[img * 4 + 0], x2 = crops[img * 4 + 1];
  int y1 = crops[img * 4 + 2], y2 = crops[img * 4 + 3];
  float ys = (float)y1 + (float)(yy * (y2 - 1 - y1)) / 223.f;
  float xs = (float)x1 + (float)(xx * (x2 - 1 - x1)) / 223.f;
  int ylo = (int)floorf(ys); if (ylo < 0) ylo = 0; if (ylo > 223) ylo = 223;
  int yhi = ylo + 1; if (yhi > 223) yhi = 223;
  float yf = ys - (float)ylo;
  int xlo = (int)floorf(xs); if (xlo < 0) xlo = 0; if (xlo > 223) xlo = 223;
  int xhi = xlo + 1; if (xhi > 223) xhi = 223;
  float xf = xs - (float)xlo;
  const float* im = in + ((size_t)b * 3 + c) * 50176;
  float r0 = im[ylo * 224 + xlo] * (1.f - yf) + im[yhi * 224 + xlo] * yf;
  float r1 = im[ylo * 224 + xhi] * (1.f - yf) + im[yhi * 224 + xhi] * yf;
  lin[idx] = r0 * (1.f - xf) + r1 * xf;
}

// ---------------- final heads, wave-parallel (continuous path; R10-validated)
__global__ __launch_bounds__(64)
void final_v2_k(const float* __restrict__ lf12,   // (12,2048), order s*4+b
                const float* __restrict__ gfbuf,  // (12,256)
                const float* __restrict__ w_ord1, const float* __restrict__ b_ord1,
                const float* __restrict__ w_fam1, const float* __restrict__ b_fam1,
                const float* __restrict__ w_sp1,  const float* __restrict__ b_sp1,
                float* __restrict__ out)
{
  int id = blockIdx.x;
  if (id >= 1004) return;
  int s, b, o; const float *w1, *b1;
  if (id < 800)      { s = 2; o = id % 200;        b = id / 200;        w1 = w_sp1;  b1 = b_sp1; }
  else if (id < 952) { s = 1; o = (id-800) % 38;   b = (id-800) / 38;   w1 = w_fam1; b1 = b_fam1; }
  else               { s = 0; o = (id-952) % 13;   b = (id-952) / 13;   w1 = w_ord1; b1 = b_ord1; }
  const int lane = threadIdx.x;
  const float* wr = w1 + (size_t)o * 2048;
  const float* lfc = lf12 + (size_t)(s * 4 + b) * 2048;
  float p1 = 0.f, p2 = 0.f;
  for (int c = lane; c < 2048; c += 64) p1 = fmaf(lfc[c], wr[c], p1);
  if (s > 0) {
    const float* lfp = lf12 + (size_t)((s - 1) * 4 + b) * 2048;
    for (int c = lane; c < 2048; c += 64) p2 = fmaf(lfp[c], wr[c], p2);
  }
  #pragma unroll
  for (int off = 32; off > 0; off >>= 1) {
    p1 += __shfl_down(p1, off);
    p2 += __shfl_down(p2, off);
  }
  if (lane == 0) {
    float ls = b1[o] + p1;
    if (s > 0) ls += b1[o] + p2;
    out[id] = (gfbuf[(size_t)(s * 4 + b) * 256 + o] + ls) * 0.5f;
  }
}

// =====================================================================================

static inline int nblk(long long total) { return (int)((total + TPB - 1) / TPB); }
static inline int ntile(int total, int t) { return (total + t - 1) / t; }

extern "C" void kernel_launch(void* const* d_in, const int* in_sizes, int n_in,
                              void* d_out, int out_size, void* d_ws, size_t ws_size,
                              hipStream_t stream)
{
  const float* inputs = (const float*)d_in[0];
  const float* bw1 = (const float*)d_in[1];  const float* bb1 = (const float*)d_in[2];
  const float* bw2 = (const float*)d_in[3];  const float* bb2 = (const float*)d_in[4];
  const float* bw3 = (const float*)d_in[5];  const float* bb3 = (const float*)d_in[6];
  const float* bw4 = (const float*)d_in[7];  const float* bb4 = (const float*)d_in[8];
  const float* w_ord  = (const float*)d_in[9];   const float* b_ord  = (const float*)d_in[10];
  const float* w_ord1 = (const float*)d_in[11];  const float* b_ord1 = (const float*)d_in[12];
  const float* w_fam  = (const float*)d_in[13];  const float* b_fam  = (const float*)d_in[14];
  const float* w_fam1 = (const float*)d_in[15];  const float* b_fam1 = (const float*)d_in[16];
  const float* w_sp   = (const float*)d_in[17];  const float* b_sp   = (const float*)d_in[18];
  const float* w_sp1  = (const float*)d_in[19];  const float* b_sp1  = (const float*)d_in[20];
  float* out = (float*)d_out;

  float* ws = (float*)d_ws;
  size_t o_x1 = 0;
  size_t o_x2 = o_x1 + (size_t)12 * 256 * 3136;
  size_t o_x3 = o_x2 + (size_t)12 * 512 * 784;
  size_t o_x4 = o_x3 + (size_t)12 * 1024 * 196;
  size_t o_gvec = o_x4 + (size_t)12 * 2048 * 49;
  size_t o_gf = o_gvec + 4 * 2048;
  size_t o_lf = o_gf + 12 * 256;
  size_t o_crop = o_lf + 12 * 2048;
  size_t o_wbf1 = o_crop + 64;                  // 256*160 bf16 = 20480 floats
  float* x1 = ws + o_x1;
  float* x2 = ws + o_x2;
  float* x3 = ws + o_x3;
  float* x4 = ws + o_x4;        // run0: fmap (4,2048,49); run1: (12,2048,49)
  float* gvec = ws + o_gvec;
  float* gfbuf = ws + o_gf;
  float* lf12 = ws + o_lf;
  int* crops = (int*)(ws + o_crop);
  float* lin = ws + o_x2;       // (12,3,224,224) overlaps x2; dead before run-1 conv2
  // bf16 weights in regions dead at their use time (R6-validated liveness):
  unsigned short* wbf1 = (unsigned short*)(ws + o_wbf1);  // 256x160 (padded K)
  unsigned short* wbf2 = (unsigned short*)x3;   // 512*2304
  unsigned short* wbf3 = (unsigned short*)x4;   // 1024*512
  unsigned short* wbf4 = (unsigned short*)x1;   // 2048*1024
  // transposed fmap (4,49,2048) aliases x1 (R15-validated liveness)
  float* fmT = x1;

  // ---- weight prep (run-1 conv1 weights, padded K 147->160)
  cvt_bf16_pad_k<<<nblk(256 * 160), TPB, 0, stream>>>(bw1, wbf1, 256, 147, 160);

  // ---- run 0: backbone on inputs (N=4) — bit-exact decision-path numerics
  {
    int np1 = 4 * 56 * 56;    // 12544
    conv_igemm_k<7,7,4,1,true><<<dim3(ntile(np1,64), 2), 256, 0, stream>>>(inputs, bw1, bb1, x1, 3, 256, 224, 56, np1, 147);
    conv3x3s2_r0_k<<<1596, 256, 0, stream>>>(x1, bw2, bb2, x2);
    int np3 = 4 * 14 * 14;    // 784
    conv1x1_igemm32_k<<<dim3(ntile(np3,64), 32), 256, 0, stream>>>(x2, bw3, bb3, x3, 512, 1024, 28, 14, np3);
    int np4 = 4 * 7 * 7;      // 196
    conv1x1_igemm32_k<<<dim3(ntile(np4,64), 64), 256, 0, stream>>>(x3, bw4, bb4, x4, 1024, 2048, 14, 7, np4);
  }
  pool_k<<<nblk(4 * 2048), TPB, 0, stream>>>(x4, gvec, 4 * 2048);

  // ---- stage heads on pooled features; CAM -> crops (all 3 stages at once)
  gf_k<<<nblk(12 * 256), TPB, 0, stream>>>(gvec, w_ord, b_ord, w_fam, b_fam, w_sp, b_sp, gfbuf);
  transpose_fm_k<<<nblk(4 * 49 * 2048), TPB, 0, stream>>>(x4, fmT);
  cam_k<<<12, TPB, 0, stream>>>(fmT, gfbuf, w_ord, b_ord, w_fam, b_fam, w_sp, b_sp, crops);
  crop_resize_k<<<nblk((long long)12 * 3 * 224 * 224), TPB, 0, stream>>>(inputs, crops, lin);

  // ---- run 1: backbone on the 12 cropped images — bf16 MFMA BM=256 (continuous path)
  {
    int np1 = 12 * 56 * 56;   // 37632 = 588*64
    conv_mfma4_k<7,7,4,1><<<dim3(588, 1), 256, 0, stream>>>(lin, wbf1, bb1, x1, 3, 256, 224, 56, np1, 160, 147);

    cvt_bf16_k<<<nblk(512 * 2304), TPB, 0, stream>>>(bw2, wbf2, 512 * 2304);
    int np2 = 12 * 28 * 28;   // 9408 = 147*64
    conv_mfma4_k<3,3,2,0><<<dim3(147, 2), 256, 0, stream>>>(x1, wbf2, bb2, x2, 256, 512, 56, 28, np2, 2304, 2304);

    cvt_bf16_k<<<nblk(1024 * 512), TPB, 0, stream>>>(bw3, wbf3, 1024 * 512);
    int np3 = 12 * 14 * 14;   // 2352
    conv_mfma4_k<1,1,2,0><<<dim3(ntile(np3,64), 4), 256, 0, stream>>>(x2, wbf3, bb3, x3, 512, 1024, 28, 14, np3, 512, 512);

    cvt_bf16_k<<<nblk(2048 * 1024), TPB, 0, stream>>>(bw4, wbf4, 2048 * 1024);
    int np4 = 12 * 7 * 7;     // 588
    conv_mfma4_k<1,1,2,0><<<dim3(ntile(np4,64), 8), 256, 0, stream>>>(x3, wbf4, bb4, x4, 1024, 2048, 14, 7, np4, 1024, 1024);
  }
  pool_k<<<nblk(12 * 2048), TPB, 0, stream>>>(x4, lf12, 12 * 2048);

  // ---- final outputs: f_sp (4x200), f_fam (4x38), f_ord (4x13) — wave-parallel
  final_v2_k<<<1004, 64, 0, stream>>>(lf12, gfbuf, w_ord1, b_ord1, w_fam1, b_fam1, w_sp1, b_sp1, out);
}

// Round 17
// 1923.549 us; speedup vs baseline: 1.0172x; 1.0172x over previous
//
#include <hip/hip_runtime.h>
#include <hip/hip_bf16.h>
#include <math.h>

#define TPB 256

typedef __attribute__((ext_vector_type(8))) short s16x8;
typedef __attribute__((ext_vector_type(8))) unsigned short u16x8;
typedef __attribute__((ext_vector_type(4))) float f32x4;

// =====================================================================================
// RUN-0 conv3x3 — EXACT R11 kernel (888us, VGPR 20, occ 67%; best of the R11-R14 sweep:
// occupancy dominates ILP on this latency-bound gather). FP statements R4-frozen
// (1-ulp obj_loc knife-edge; R3/R5/R7 restructures all flipped it). PERMANENTLY CLOSED.
// =====================================================================================
__global__ void conv3x3s2_r0_k(const float* __restrict__ in, const float* __restrict__ w,
                               const float* __restrict__ bias, float* __restrict__ out)
{
  const int d = blockIdx.x;
  const int xcd = d & 7;
  const int n = xcd & 3;
  const int ipair = ((d >> 3) << 1) | (xcd >> 2);
  const int wave = ipair * 4 + (threadIdx.x >> 6);   // [0, 1596) = 57 oc-tiles x 28 oy
  const int oct = wave % 57;
  const int oy = wave / 57;
  const int lane = threadIdx.x & 63;
  const int oc_low = lane / 7;                        // 0..8 active, 9 (lane 63) idle
  const int oxg = lane - oc_low * 7;
  const int oc = oct * 9 + oc_low;
  if (oc_low > 8 || oc >= 512) return;

  const float* inp = in + (size_t)n * 256 * 3136;
  const float* wp = w + (size_t)oc * 2304;
  float b0 = bias[oc];
  float acc0 = b0, acc1 = b0, acc2 = b0, acc3 = b0;
  int xb0 = oxg * 8;
  #pragma unroll 4
  for (int ic = 0; ic < 256; ic++) {
    const float* ich = inp + (size_t)ic * 3136;
    const float* wr = wp + ic * 9;
    #pragma unroll
    for (int ky = 0; ky < 3; ky++) {
      int iy = oy * 2 + ky;
      if (iy >= 56) continue;
      const float* row = ich + iy * 56;
      float w0 = wr[ky * 3 + 0], w1 = wr[ky * 3 + 1], w2 = wr[ky * 3 + 2];
      {
        int xb = xb0 + 0;
        acc0 += row[xb] * w0 + row[xb + 1] * w1 + row[xb + 2] * w2;
      }
      {
        int xb = xb0 + 2;
        acc1 += row[xb] * w0 + row[xb + 1] * w1 + row[xb + 2] * w2;
      }
      {
        int xb = xb0 + 4;
        acc2 += row[xb] * w0 + row[xb + 1] * w1 + row[xb + 2] * w2;
      }
      {
        int xb = xb0 + 6;
        acc3 += row[xb] * w0 + row[xb + 1] * w1;
        if (xb + 2 < 56) acc3 += row[xb + 2] * w2;
      }
    }
  }
  float* op = out + (((size_t)n * 512 + oc) * 28 + oy) * 28 + oxg * 4;
  op[0] = fmaxf(acc0, 0.f);
  op[1] = fmaxf(acc1, 0.f);
  op[2] = fmaxf(acc2, 0.f);
  op[3] = fmaxf(acc3, 0.f);
}

// =====================================================================================
// fp32 implicit-GEMM conv (BM=128), BINIT bias-seeded: bit-exact single-fma chain
// (R6-validated). Used for run-0 conv7x7 only.
// =====================================================================================
template<int KH, int KW, int STRIDE, int PADL, bool BINIT>
__global__ __launch_bounds__(256)
void conv_igemm_k(const float* __restrict__ in, const float* __restrict__ w,
                  const float* __restrict__ bias, float* __restrict__ out,
                  int Cin, int Cout, int Hin, int OH, int Np, int K)
{
  __shared__ float As[16][136];
  __shared__ float Bs[16][64];

  const int tid = threadIdx.x;
  const int bx = blockIdx.x;
  const int by = blockIdx.y;
  const int OHW = OH * OH;
  const int HinHin = Hin * Hin;

  const int n_sub = tid & 63;
  const int kq = tid >> 6;
  const int n_g = bx * 64 + n_sub;
  const bool nvalid = (n_g < Np);
  const int n_c = nvalid ? n_g : 0;
  const int img = n_c / OHW;
  const int p = n_c - img * OHW;
  const int oy = p / OH;
  const int ox = p - oy * OH;
  const int iy0 = oy * STRIDE - PADL;
  const int ix0 = ox * STRIDE - PADL;
  const float* inb = in + (size_t)img * Cin * HinHin;

  const int ks = tid & 15;
  const int msq = tid >> 4;
  const int m_base = by * 128;

  const int m0 = (tid >> 4) * 8;
  const int n0 = (tid & 15) * 4;

  float acc[8][4];
  #pragma unroll
  for (int i = 0; i < 8; i++) {
    const float init = BINIT ? bias[m_base + m0 + i] : 0.f;
    #pragma unroll
    for (int j = 0; j < 4; j++) acc[i][j] = init;
  }

  const int KT = (K + 15) >> 4;
  for (int kt = 0; kt < KT; kt++) {
    const int k0 = kt * 16;
    #pragma unroll
    for (int j = 0; j < 8; j++) {
      const int m = msq + 16 * j;
      const int k = k0 + ks;
      float v = 0.f;
      if (k < K) v = w[(size_t)(m_base + m) * K + k];
      As[ks][m] = v;
    }
    #pragma unroll
    for (int j = 0; j < 4; j++) {
      const int k = k0 + kq * 4 + j;
      float v = 0.f;
      if (nvalid && k < K) {
        const int c = k / (KH * KW);
        const int r = k - c * (KH * KW);
        const int ky = r / KW;
        const int kx = r - ky * KW;
        const int iy = iy0 + ky;
        const int ix = ix0 + kx;
        if (iy >= 0 && iy < Hin && ix >= 0 && ix < Hin)
          v = inb[(size_t)c * HinHin + iy * Hin + ix];
      }
      Bs[kq * 4 + j][n_sub] = v;
    }
    __syncthreads();
    #pragma unroll
    for (int k = 0; k < 16; k++) {
      float a_[8], b_[4];
      #pragma unroll
      for (int i = 0; i < 8; i++) a_[i] = As[k][m0 + i];
      #pragma unroll
      for (int j = 0; j < 4; j++) b_[j] = Bs[k][n0 + j];
      #pragma unroll
      for (int i = 0; i < 8; i++)
        #pragma unroll
        for (int j = 0; j < 4; j++) acc[i][j] += a_[i] * b_[j];
    }
    __syncthreads();
  }

  #pragma unroll
  for (int i = 0; i < 8; i++) {
    const int m = m_base + m0 + i;
    const float bv = BINIT ? 0.f : bias[m];
    #pragma unroll
    for (int j = 0; j < 4; j++) {
      const int nn = bx * 64 + n0 + j;
      if (nn < Np) {
        const int img2 = nn / OHW;
        const int pp = nn - img2 * OHW;
        const float v = BINIT ? acc[i][j] : (acc[i][j] + bv);
        out[((size_t)img2 * Cout + m) * OHW + pp] = fmaxf(v, 0.f);
      }
    }
  }
}

// =====================================================================================
// 1x1 stride-2 conv as GEMM, BM=32/BN=64/BK=32, bias-seeded bit-exact fma chain
// (R10-validated). Run-0 conv3/conv4.
// =====================================================================================
__global__ __launch_bounds__(256)
void conv1x1_igemm32_k(const float* __restrict__ in, const float* __restrict__ w,
                       const float* __restrict__ bias, float* __restrict__ out,
                       int Cin, int Cout, int Hin, int OH, int Np)
{
  __shared__ float As[32][33];   // [k][m]
  __shared__ float Bs[32][65];   // [k][n]

  const int tid = threadIdx.x;
  const int bx = blockIdx.x;
  const int by = blockIdx.y;
  const int OHW = OH * OH;
  const int HH = Hin * Hin;
  const int m_base = by * 32;

  const int am = tid >> 3;
  const int ak0 = (tid & 7) * 4;
  const int bk = tid >> 3;
  const int bn0 = (tid & 7) * 8;
  const int cn = tid & 63;
  const int cm0 = (tid >> 6) * 8;
  const int n_g = bx * 64 + cn;

  float acc[8];
  #pragma unroll
  for (int i = 0; i < 8; i++) acc[i] = bias[m_base + cm0 + i];

  int bpix[8]; bool bval[8];
  #pragma unroll
  for (int j = 0; j < 8; j++) {
    int n = bx * 64 + bn0 + j;
    bval[j] = (n < Np);
    int nn = bval[j] ? n : 0;
    int img = nn / OHW; int pp = nn - img * OHW; int oy = pp / OH; int ox = pp - oy * OH;
    bpix[j] = img * Cin * HH + (2 * oy) * Hin + 2 * ox;
  }

  for (int k0 = 0; k0 < Cin; k0 += 32) {
    #pragma unroll
    for (int j = 0; j < 4; j++)
      As[ak0 + j][am] = w[(size_t)(m_base + am) * Cin + k0 + ak0 + j];
    #pragma unroll
    for (int j = 0; j < 8; j++)
      Bs[bk][bn0 + j] = bval[j] ? in[(size_t)(k0 + bk) * HH + bpix[j]] : 0.f;
    __syncthreads();
    #pragma unroll
    for (int k = 0; k < 32; k++) {
      float b = Bs[k][cn];
      #pragma unroll
      for (int i = 0; i < 8; i++) acc[i] += As[k][cm0 + i] * b;
    }
    __syncthreads();
  }

  if (n_g < Np) {
    int img = n_g / OHW; int pp = n_g - img * OHW;
    #pragma unroll
    for (int i = 0; i < 8; i++)
      out[((size_t)img * Cout + m_base + cm0 + i) * OHW + pp] = fmaxf(acc[i], 0.f);
  }
}

// =====================================================================================
// fp32 -> bf16 weight conversion (RNE); padded variant zero-fills k in [kin, kout)
// =====================================================================================
__global__ void cvt_bf16_k(const float* __restrict__ in, unsigned short* __restrict__ out, int n)
{
  int i = blockIdx.x * blockDim.x + threadIdx.x;
  if (i >= n) return;
  __hip_bfloat16 h = __float2bfloat16(in[i]);
  out[i] = *reinterpret_cast<unsigned short*>(&h);
}

__global__ void cvt_bf16_pad_k(const float* __restrict__ in, unsigned short* __restrict__ out,
                               int rows, int kin, int kout)
{
  int i = blockIdx.x * blockDim.x + threadIdx.x;
  if (i >= rows * kout) return;
  int r = i / kout, k = i - r * kout;
  unsigned short v = 0;
  if (k < kin) {
    __hip_bfloat16 h = __float2bfloat16(in[(size_t)r * kin + k]);
    v = *reinterpret_cast<unsigned short*>(&h);
  }
  out[i] = v;
}

// =====================================================================================
// fmap transpose: (4,2048,49) -> (4,49,2048). Pure data movement (bit-exact).
// =====================================================================================
__global__ void transpose_fm_k(const float* __restrict__ in, float* __restrict__ out)
{
  int idx = blockIdx.x * blockDim.x + threadIdx.x;
  if (idx >= 4 * 49 * 2048) return;
  const int c = idx & 2047;
  const int t = idx >> 11;          // b*49 + p
  const int b = t / 49;
  const int p = t - b * 49;
  out[idx] = in[((size_t)b * 2048 + c) * 49 + p];
}

// =====================================================================================
// bf16 MFMA implicit-GEMM conv, BM=128 x BN=64, BK=32, software-pipelined gather
// (R11/R15-validated; R16's BM=256 A/B showed regression -> BM=128 is optimal).
// =====================================================================================
template<int KH, int KW, int STRIDE, int PADL>
__global__ __launch_bounds__(256)
void conv_mfma2_k(const float* __restrict__ in, const unsigned short* __restrict__ wbf,
                  const float* __restrict__ bias, float* __restrict__ out,
                  int Cin, int Cout, int Hin, int OH, int Np, int K, int kreal)
{
  __shared__ unsigned short As[128 * 40];  // [m][k], rows padded to 40
  __shared__ unsigned short Bs[64 * 40];   // [n][k]

  const int tid = threadIdx.x;
  const int bx = blockIdx.x;
  const int by = blockIdx.y;
  const int OHW = OH * OH;
  const int HH = Hin * Hin;
  const int m_base = by * 128;

  const int n_sub = tid & 63;
  const int kq = tid >> 6;
  const int n_g = bx * 64 + n_sub;
  const bool nv = (n_g < Np);
  const int n_c = nv ? n_g : 0;
  const int img = n_c / OHW;
  const int p = n_c - img * OHW;
  const int oy = p / OH;
  const int ox = p - oy * OH;
  const int iy0 = oy * STRIDE - PADL;
  const int ix0 = ox * STRIDE - PADL;
  const float* inb = in + (size_t)img * Cin * HH;

  const int arow = tid >> 1;           // 0..127
  const int akoff = (tid & 1) * 16;    // 0 or 16

  const int wv = tid >> 6;
  const int ln = tid & 63;
  const int lr = ln & 15;
  const int lq = ln >> 4;

  f32x4 acc[2][4];
  #pragma unroll
  for (int h = 0; h < 2; h++)
    #pragma unroll
    for (int nf = 0; nf < 4; nf++) acc[h][nf] = (f32x4){0.f, 0.f, 0.f, 0.f};

#define GATHER_A(K0, A0, A1)                                                      \
  {                                                                               \
    const unsigned short* wr_ = wbf + (size_t)(m_base + arow) * K + (K0) + akoff; \
    A0 = *(const u16x8*)(wr_);                                                    \
    A1 = *(const u16x8*)(wr_ + 8);                                                \
  }
#define GATHER_B(K0, BV)                                                          \
  {                                                                               \
    _Pragma("unroll")                                                             \
    for (int i = 0; i < 8; i++) {                                                 \
      const int k = (K0) + kq * 8 + i;                                            \
      float v = 0.f;                                                              \
      if (nv && k < kreal) {                                                      \
        const int c = k / (KH * KW);                                              \
        const int r = k - c * (KH * KW);                                          \
        const int ky = r / KW;                                                    \
        const int kx = r - ky * KW;                                               \
        const int iy = iy0 + ky;                                                  \
        const int ix = ix0 + kx;                                                  \
        if (iy >= 0 && iy < Hin && ix >= 0 && ix < Hin)                           \
          v = inb[(size_t)c * HH + iy * Hin + ix];                                \
      }                                                                           \
      __hip_bfloat16 h_ = __float2bfloat16(v);                                    \
      BV[i] = *reinterpret_cast<unsigned short*>(&h_);                            \
    }                                                                             \
  }

  u16x8 a0, a1, bv;
  GATHER_A(0, a0, a1);
  GATHER_B(0, bv);

  for (int k0 = 0; k0 < K; k0 += 32) {
    *(u16x8*)&As[arow * 40 + akoff] = a0;
    *(u16x8*)&As[arow * 40 + akoff + 8] = a1;
    *(u16x8*)&Bs[n_sub * 40 + kq * 8] = bv;
    __syncthreads();

    if (k0 + 32 < K) { GATHER_A(k0 + 32, a0, a1); GATHER_B(k0 + 32, bv); }

    s16x8 am0 = *(const s16x8*)&As[(wv * 16 + lr) * 40 + lq * 8];
    s16x8 am1 = *(const s16x8*)&As[(64 + wv * 16 + lr) * 40 + lq * 8];
    #pragma unroll
    for (int nf = 0; nf < 4; nf++) {
      s16x8 b = *(const s16x8*)&Bs[(nf * 16 + lr) * 40 + lq * 8];
      acc[0][nf] = __builtin_amdgcn_mfma_f32_16x16x32_bf16(am0, b, acc[0][nf], 0, 0, 0);
      acc[1][nf] = __builtin_amdgcn_mfma_f32_16x16x32_bf16(am1, b, acc[1][nf], 0, 0, 0);
    }
    __syncthreads();
  }
#undef GATHER_A
#undef GATHER_B

  #pragma unroll
  for (int h = 0; h < 2; h++) {
    #pragma unroll
    for (int nf = 0; nf < 4; nf++) {
      const int n_gl = bx * 64 + nf * 16 + lr;
      if (n_gl < Np) {
        const int img2 = n_gl / OHW;
        const int pp = n_gl - img2 * OHW;
        #pragma unroll
        for (int r = 0; r < 4; r++) {
          const int m = m_base + h * 64 + wv * 16 + lq * 4 + r;
          out[((size_t)img2 * Cout + m) * OHW + pp] = fmaxf(acc[h][nf][r] + bias[m], 0.f);
        }
      }
    }
  }
}

// ---------------- global average pool (X,2048,7,7) -> (X,2048)
__global__ void pool_k(const float* __restrict__ in, float* __restrict__ out, int total)
{
  int idx = blockIdx.x * blockDim.x + threadIdx.x;
  if (idx >= total) return;
  const float* p = in + (size_t)idx * 49;
  float s = 0.f;
  #pragma unroll
  for (int i = 0; i < 49; i++) s += p[i];
  out[idx] = s / 49.f;
}

// ---------------- gf = gvec @ wc.T + bc (DECISION PATH: serial c-order chain, frozen)
__global__ void gf_k(const float* __restrict__ gvec,
                     const float* __restrict__ w_ord, const float* __restrict__ b_ord,
                     const float* __restrict__ w_fam, const float* __restrict__ b_fam,
                     const float* __restrict__ w_sp,  const float* __restrict__ b_sp,
                     float* __restrict__ gfbuf)
{
  int idx = blockIdx.x * blockDim.x + threadIdx.x;
  if (idx >= 12 * 256) return;
  int o = idx % 256; int t = idx / 256; int b = t % 4; int s = t / 4;
  int nc = (s == 0) ? 13 : ((s == 1) ? 38 : 200);
  if (o >= nc) return;
  const float* w = (s == 0) ? w_ord : ((s == 1) ? w_fam : w_sp);
  const float* bb = (s == 0) ? b_ord : ((s == 1) ? b_fam : b_sp);
  float acc = bb[o];
  const float* g = gvec + (size_t)b * 2048;
  const float* wr = w + (size_t)o * 2048;
  for (int c = 0; c < 2048; c++) acc += g[c] * wr[c];
  gfbuf[idx] = acc;
}

// ---------------- obj_loc, faithful to the JAX reference (serial, one thread)
__device__ void obj_loc_dev(const float* sc, int* zmin_o, int* zmax_o)
{
  const int n = 224, minsize = 28, defmax = 196;
  float mn = sc[0], mx = sc[0];
  for (int i = 1; i < n; i++) { mn = fminf(mn, sc[i]); mx = fmaxf(mx, sc[i]); }
  float den = (mx == mn) ? mx : (mx - mn);
#define NV(i) (((mx == mn) ? sc[i] : (sc[i] - mn)) / den)
#define SGN(v) (((v) > 0.5f) ? 1 : (((v) < 0.5f) ? -1 : 0))

  int k = 0; float M = -INFINITY;
  {
    float v = NV(0); int sg = SGN(v);
    float smax = -INFINITY; int cnt = 0;
    for (int j = 0; j < n; j++) {
      int indj = 0; float vn = 0.f; int sgn_nx = 0;
      if (j < n - 1) { vn = NV(j + 1); sgn_nx = SGN(vn); int d = sgn_nx - sg; indj = (d == 2 || d == -2); }
      if (indj) { if (cnt > 0) M = fmaxf(M, smax); k++; smax = -INFINITY; cnt = 0; }
      smax = fmaxf(smax, v); cnt++;
      if (j < n - 1) { v = vn; sg = sgn_nx; }
    }
    if (cnt > 0) M = fmaxf(M, smax);
  }

  int zmin, zmax;
  if (k == 0) { zmin = minsize; zmax = defmax; }
  else {
    int bestlen = -1;
    {
      float v = NV(0); int sg = SGN(v);
      float smax = -INFINITY; int cnt = 0;
      for (int j = 0; j < n; j++) {
        int indj = 0; float vn = 0.f; int sgn_nx = 0;
        if (j < n - 1) { vn = NV(j + 1); sgn_nx = SGN(vn); int d = sgn_nx - sg; indj = (d == 2 || d == -2); }
        if (indj) { if (cnt > 0 && smax == M && cnt > bestlen) bestlen = cnt; smax = -INFINITY; cnt = 0; }
        smax = fmaxf(smax, v); cnt++;
        if (j < n - 1) { v = vn; sg = sgn_nx; }
      }
      if (cnt > 0 && smax == M && cnt > bestlen) bestlen = cnt;
    }
    int bestorder = 1 << 30; int bzmin = 0, bzmax = 0;
    {
      float v = NV(0); int sg = SGN(v);
      float smax = -INFINITY; int cnt = 0; int start = 0; int sid = 0;
      for (int j = 0; j < n; j++) {
        int indj = 0; float vn = 0.f; int sgn_nx = 0;
        if (j < n - 1) { vn = NV(j + 1); sgn_nx = SGN(vn); int d = sgn_nx - sg; indj = (d == 2 || d == -2); }
        if (indj) {
          if (cnt > 0 && smax == M && cnt == bestlen) {
            int order = (sid == 0) ? 0 : ((sid == k) ? 1 : (sid + 1));
            if (order < bestorder) { bestorder = order; bzmin = start; bzmax = j; }
          }
          sid++; start = j; smax = -INFINITY; cnt = 0;
        }
        smax = fmaxf(smax, v); cnt++;
        if (j < n - 1) { v = vn; sg = sgn_nx; }
      }
      if (cnt > 0 && smax == M && cnt == bestlen) {
        int order = (sid == 0) ? 0 : ((sid == k) ? 1 : (sid + 1));
        if (order < bestorder) { bestorder = order; bzmin = start; bzmax = n; }
      }
    }
    zmin = bzmin; zmax = bzmax;
    int pad = minsize - (zmax - zmin);
    int hp = (pad + 1) / 2;
    int need = ((zmax - zmin) <= minsize);
    if (need && (zmin > hp) && ((n - zmax) > pad)) { zmin = zmin - hp + 1; zmax = zmax + hp; }
    if (need && (zmin < hp)) { zmin = 0; zmax = minsize; }
    if (need && ((n - zmax) < hp)) { zmin = n - minsize + 1; zmax = n; }
  }
  *zmin_o = zmin; *zmax_o = zmax;
#undef NV
#undef SGN
}

// ---------------- per (stage,batch): argmax, 7x7 CAM, upsample-max, obj_loc -> crops
// fmT is the transposed fmap (4,49,2048) — R15-validated bit-exact layout change.
__global__ void cam_k(const float* __restrict__ fmT,      // (4,49,2048)
                      const float* __restrict__ gfbuf,    // (12,256)
                      const float* __restrict__ w_ord, const float* __restrict__ b_ord,
                      const float* __restrict__ w_fam, const float* __restrict__ b_fam,
                      const float* __restrict__ w_sp,  const float* __restrict__ b_sp,
                      int* __restrict__ crops)
{
  int bid = blockIdx.x;        // 0..11
  int s = bid / 4, b = bid % 4;
  int nc = (s == 0) ? 13 : ((s == 1) ? 38 : 200);
  const float* wc = (s == 0) ? w_ord : ((s == 1) ? w_fam : w_sp);
  const float* bc = (s == 0) ? b_ord : ((s == 1) ? b_fam : b_sp);

  __shared__ float cam7[49];
  __shared__ float wsc[224];
  __shared__ float hsc[224];
  __shared__ int top_s;
  int tid = threadIdx.x;

  if (tid == 0) {
    const float* g = gfbuf + (size_t)bid * 256;
    int best = 0; float bv = g[0];
    for (int i = 1; i < nc; i++) { if (g[i] > bv) { bv = g[i]; best = i; } }
    top_s = best;
  }
  __syncthreads();
  int top = top_s;

  if (tid < 49) {
    const float* fp = fmT + ((size_t)(b * 49) + tid) * 2048;
    const float* wr = wc + (size_t)top * 2048;
    float acc = bc[top];
    for (int c = 0; c < 2048; c++) acc += fp[c] * wr[c];
    cam7[tid] = 1.f / (1.f + expf(-acc));
  }
  __syncthreads();

  if (tid < 224) {
    {
      int xx = tid;
      float xsf = (float)(xx * 6) / 223.f;
      int xlo = (int)floorf(xsf); if (xlo > 6) xlo = 6; if (xlo < 0) xlo = 0;
      int xhi = xlo + 1; if (xhi > 6) xhi = 6;
      float xf = xsf - (float)xlo;
      float m = -INFINITY;
      for (int yy = 0; yy < 224; yy++) {
        float ysf = (float)(yy * 6) / 223.f;
        int ylo = (int)floorf(ysf); if (ylo > 6) ylo = 6; if (ylo < 0) ylo = 0;
        int yhi = ylo + 1; if (yhi > 6) yhi = 6;
        float yf = ysf - (float)ylo;
        float r0 = cam7[ylo * 7 + xlo] * (1.f - yf) + cam7[yhi * 7 + xlo] * yf;
        float r1 = cam7[ylo * 7 + xhi] * (1.f - yf) + cam7[yhi * 7 + xhi] * yf;
        m = fmaxf(m, r0 * (1.f - xf) + r1 * xf);
      }
      wsc[xx] = m;
    }
    {
      int yy = tid;
      float ysf = (float)(yy * 6) / 223.f;
      int ylo = (int)floorf(ysf); if (ylo > 6) ylo = 6; if (ylo < 0) ylo = 0;
      int yhi = ylo + 1; if (yhi > 6) yhi = 6;
      float yf = ysf - (float)ylo;
      float m = -INFINITY;
      for (int xx = 0; xx < 224; xx++) {
        float xsf = (float)(xx * 6) / 223.f;
        int xlo = (int)floorf(xsf); if (xlo > 6) xlo = 6; if (xlo < 0) xlo = 0;
        int xhi = xlo + 1; if (xhi > 6) xhi = 6;
        float xf = xsf - (float)xlo;
        float r0 = cam7[ylo * 7 + xlo] * (1.f - yf) + cam7[yhi * 7 + xlo] * yf;
        float r1 = cam7[ylo * 7 + xhi] * (1.f - yf) + cam7[yhi * 7 + xhi] * yf;
        m = fmaxf(m, r0 * (1.f - xf) + r1 * xf);
      }
      hsc[yy] = m;
    }
  }
  __syncthreads();

  if (tid == 0) {
    int zmin, zmax; obj_loc_dev(wsc, &zmin, &zmax);
    crops[bid * 4 + 0] = zmin; crops[bid * 4 + 1] = zmax;
  } else if (tid == 1) {
    int zmin, zmax; obj_loc_dev(hsc, &zmin, &zmax);
    crops[bid * 4 + 2] = zmin; crops[bid * 4 + 3] = zmax;
  }
}

// ---------------- bilinear (align_corners) crop-resize: inputs (4,3,224,224) -> lin (12,3,224,224)
__global__ void crop_resize_k(const float* __restrict__ in, const int* __restrict__ crops,
                              float* __restrict__ lin)
{
  int idx = blockIdx.x * blockDim.x + threadIdx.x;
  int total = 12 * 3 * 224 * 224;
  if (idx >= total) return;
  int xx = idx % 224; int t = idx / 224; int yy = t % 224; t /= 224; int c = t % 3; int img = t / 3;
  int b = img % 4;
  int x1 = crops[img * 4 + 0], x2 = crops[img * 4 + 1];
  int y1 = crops[img * 4 + 2], y2 = crops[img * 4 + 3];
  float ys = (float)y1 + (float)(yy * (y2 - 1 - y1)) / 223.f;
  float xs = (float)x1 + (float)(xx * (x2 - 1 - x1)) / 223.f;
  int ylo = (int)floorf(ys); if (ylo < 0) ylo = 0; if (ylo > 223) ylo = 223;
  int yhi = ylo + 1; if (yhi > 223) yhi = 223;
  float yf = ys - (float)ylo;
  int xlo = (int)floorf(xs); if (xlo < 0) xlo = 0; if (xlo > 223) xlo = 223;
  int xhi = xlo + 1; if (xhi > 223) xhi = 223;
  float xf = xs - (float)xlo;
  const float* im = in + ((size_t)b * 3 + c) * 50176;
  float r0 = im[ylo * 224 + xlo] * (1.f - yf) + im[yhi * 224 + xlo] * yf;
  float r1 = im[ylo * 224 + xhi] * (1.f - yf) + im[yhi * 224 + xhi] * yf;
  lin[idx] = r0 * (1.f - xf) + r1 * xf;
}

// ---------------- final heads, wave-parallel (continuous path; R10-validated)
__global__ __launch_bounds__(64)
void final_v2_k(const float* __restrict__ lf12,   // (12,2048), order s*4+b
                const float* __restrict__ gfbuf,  // (12,256)
                const float* __restrict__ w_ord1, const float* __restrict__ b_ord1,
                const float* __restrict__ w_fam1, const float* __restrict__ b_fam1,
                const float* __restrict__ w_sp1,  const float* __restrict__ b_sp1,
                float* __restrict__ out)
{
  int id = blockIdx.x;
  if (id >= 1004) return;
  int s, b, o; const float *w1, *b1;
  if (id < 800)      { s = 2; o = id % 200;        b = id / 200;        w1 = w_sp1;  b1 = b_sp1; }
  else if (id < 952) { s = 1; o = (id-800) % 38;   b = (id-800) / 38;   w1 = w_fam1; b1 = b_fam1; }
  else               { s = 0; o = (id-952) % 13;   b = (id-952) / 13;   w1 = w_ord1; b1 = b_ord1; }
  const int lane = threadIdx.x;
  const float* wr = w1 + (size_t)o * 2048;
  const float* lfc = lf12 + (size_t)(s * 4 + b) * 2048;
  float p1 = 0.f, p2 = 0.f;
  for (int c = lane; c < 2048; c += 64) p1 = fmaf(lfc[c], wr[c], p1);
  if (s > 0) {
    const float* lfp = lf12 + (size_t)((s - 1) * 4 + b) * 2048;
    for (int c = lane; c < 2048; c += 64) p2 = fmaf(lfp[c], wr[c], p2);
  }
  #pragma unroll
  for (int off = 32; off > 0; off >>= 1) {
    p1 += __shfl_down(p1, off);
    p2 += __shfl_down(p2, off);
  }
  if (lane == 0) {
    float ls = b1[o] + p1;
    if (s > 0) ls += b1[o] + p2;
    out[id] = (gfbuf[(size_t)(s * 4 + b) * 256 + o] + ls) * 0.5f;
  }
}

// =====================================================================================

static inline int nblk(long long total) { return (int)((total + TPB - 1) / TPB); }
static inline int ntile(int total, int t) { return (total + t - 1) / t; }

extern "C" void kernel_launch(void* const* d_in, const int* in_sizes, int n_in,
                              void* d_out, int out_size, void* d_ws, size_t ws_size,
                              hipStream_t stream)
{
  const float* inputs = (const float*)d_in[0];
  const float* bw1 = (const float*)d_in[1];  const float* bb1 = (const float*)d_in[2];
  const float* bw2 = (const float*)d_in[3];  const float* bb2 = (const float*)d_in[4];
  const float* bw3 = (const float*)d_in[5];  const float* bb3 = (const float*)d_in[6];
  const float* bw4 = (const float*)d_in[7];  const float* bb4 = (const float*)d_in[8];
  const float* w_ord  = (const float*)d_in[9];   const float* b_ord  = (const float*)d_in[10];
  const float* w_ord1 = (const float*)d_in[11];  const float* b_ord1 = (const float*)d_in[12];
  const float* w_fam  = (const float*)d_in[13];  const float* b_fam  = (const float*)d_in[14];
  const float* w_fam1 = (const float*)d_in[15];  const float* b_fam1 = (const float*)d_in[16];
  const float* w_sp   = (const float*)d_in[17];  const float* b_sp   = (const float*)d_in[18];
  const float* w_sp1  = (const float*)d_in[19];  const float* b_sp1  = (const float*)d_in[20];
  float* out = (float*)d_out;

  float* ws = (float*)d_ws;
  size_t o_x1 = 0;
  size_t o_x2 = o_x1 + (size_t)12 * 256 * 3136;
  size_t o_x3 = o_x2 + (size_t)12 * 512 * 784;
  size_t o_x4 = o_x3 + (size_t)12 * 1024 * 196;
  size_t o_gvec = o_x4 + (size_t)12 * 2048 * 49;
  size_t o_gf = o_gvec + 4 * 2048;
  size_t o_lf = o_gf + 12 * 256;
  size_t o_crop = o_lf + 12 * 2048;
  size_t o_wbf1 = o_crop + 64;                  // 256*160 bf16 = 20480 floats
  float* x1 = ws + o_x1;
  float* x2 = ws + o_x2;
  float* x3 = ws + o_x3;
  float* x4 = ws + o_x4;        // run0: fmap (4,2048,49); run1: (12,2048,49)
  float* gvec = ws + o_gvec;
  float* gfbuf = ws + o_gf;
  float* lf12 = ws + o_lf;
  int* crops = (int*)(ws + o_crop);
  float* lin = ws + o_x2;       // (12,3,224,224) overlaps x2; dead before run-1 conv2
  // bf16 weights in regions dead at their use time (R6-validated liveness):
  unsigned short* wbf1 = (unsigned short*)(ws + o_wbf1);  // 256x160 (padded K)
  unsigned short* wbf2 = (unsigned short*)x3;   // 512*2304
  unsigned short* wbf3 = (unsigned short*)x4;   // 1024*512
  unsigned short* wbf4 = (unsigned short*)x1;   // 2048*1024
  // transposed fmap (4,49,2048) aliases x1 (R15-validated liveness)
  float* fmT = x1;

  // ---- weight prep (run-1 conv1 weights, padded K 147->160)
  cvt_bf16_pad_k<<<nblk(256 * 160), TPB, 0, stream>>>(bw1, wbf1, 256, 147, 160);

  // ---- run 0: backbone on inputs (N=4) — bit-exact decision-path numerics
  {
    int np1 = 4 * 56 * 56;    // 12544
    conv_igemm_k<7,7,4,1,true><<<dim3(ntile(np1,64), 2), 256, 0, stream>>>(inputs, bw1, bb1, x1, 3, 256, 224, 56, np1, 147);
    conv3x3s2_r0_k<<<1596, 256, 0, stream>>>(x1, bw2, bb2, x2);
    int np3 = 4 * 14 * 14;    // 784
    conv1x1_igemm32_k<<<dim3(ntile(np3,64), 32), 256, 0, stream>>>(x2, bw3, bb3, x3, 512, 1024, 28, 14, np3);
    int np4 = 4 * 7 * 7;      // 196
    conv1x1_igemm32_k<<<dim3(ntile(np4,64), 64), 256, 0, stream>>>(x3, bw4, bb4, x4, 1024, 2048, 14, 7, np4);
  }
  pool_k<<<nblk(4 * 2048), TPB, 0, stream>>>(x4, gvec, 4 * 2048);

  // ---- stage heads on pooled features; CAM -> crops (all 3 stages at once)
  gf_k<<<nblk(12 * 256), TPB, 0, stream>>>(gvec, w_ord, b_ord, w_fam, b_fam, w_sp, b_sp, gfbuf);
  transpose_fm_k<<<nblk(4 * 49 * 2048), TPB, 0, stream>>>(x4, fmT);
  cam_k<<<12, TPB, 0, stream>>>(fmT, gfbuf, w_ord, b_ord, w_fam, b_fam, w_sp, b_sp, crops);
  crop_resize_k<<<nblk((long long)12 * 3 * 224 * 224), TPB, 0, stream>>>(inputs, crops, lin);

  // ---- run 1: backbone on the 12 cropped images — bf16 MFMA BM=128 (continuous path)
  {
    int np1 = 12 * 56 * 56;   // 37632 = 588*64
    conv_mfma2_k<7,7,4,1><<<dim3(588, 2), 256, 0, stream>>>(lin, wbf1, bb1, x1, 3, 256, 224, 56, np1, 160, 147);

    cvt_bf16_k<<<nblk(512 * 2304), TPB, 0, stream>>>(bw2, wbf2, 512 * 2304);
    int np2 = 12 * 28 * 28;   // 9408 = 147*64
    conv_mfma2_k<3,3,2,0><<<dim3(147, 4), 256, 0, stream>>>(x1, wbf2, bb2, x2, 256, 512, 56, 28, np2, 2304, 2304);

    cvt_bf16_k<<<nblk(1024 * 512), TPB, 0, stream>>>(bw3, wbf3, 1024 * 512);
    int np3 = 12 * 14 * 14;   // 2352
    conv_mfma2_k<1,1,2,0><<<dim3(ntile(np3,64), 8), 256, 0, stream>>>(x2, wbf3, bb3, x3, 512, 1024, 28, 14, np3, 512, 512);

    cvt_bf16_k<<<nblk(2048 * 1024), TPB, 0, stream>>>(bw4, wbf4, 2048 * 1024);
    int np4 = 12 * 7 * 7;     // 588
    conv_mfma2_k<1,1,2,0><<<dim3(ntile(np4,64), 16), 256, 0, stream>>>(x3, wbf4, bb4, x4, 1024, 2048, 14, 7, np4, 1024, 1024);
  }
  pool_k<<<nblk(12 * 2048), TPB, 0, stream>>>(x4, lf12, 12 * 2048);

  // ---- final outputs: f_sp (4x200), f_fam (4x38), f_ord (4x13) — wave-parallel
  final_v2_k<<<1004, 64, 0, stream>>>(lf12, gfbuf, w_ord1, b_ord1, w_fam1, b_fam1, w_sp1, b_sp1, out);
}